// Round 11
// baseline (504.984 us; speedup 1.0000x reference)
//
#include <hip/hip_runtime.h>
#include <hip/hip_bf16.h>

#define BATCH 2048
#define KD 1024
#define ND 1024
#define NLEAF 64
#define BM 256
#define BN 128
// 32 kk-steps of K=32

typedef __attribute__((ext_vector_type(8))) short bf16x8;
typedef __attribute__((ext_vector_type(4))) float f32x4;
typedef __attribute__((ext_vector_type(8))) _Float16 f16x8;

// workspace layout (bytes)
#define WLB_OFF 0ULL                 // B (Wl) bf16 row-major, 128 MB
#define XB_OFF  134217728ULL         // A (x) bf16 row-major, 4 MB
#define RT_OFF  138412032ULL         // routing 512 KB
#define LG_OFF  138936320ULL         // logits fp16 (268 MB full / 64 MB grouped)

__device__ __forceinline__ unsigned short f2bf(float f) {
  unsigned int u = __float_as_uint(f);
  u += 0x7fffu + ((u >> 16) & 1u);
  return (unsigned short)(u >> 16);
}

__device__ __forceinline__ void gload_lds16(const void* g, void* l) {
  __builtin_amdgcn_global_load_lds(
      (const __attribute__((address_space(1))) unsigned int*)g,
      (__attribute__((address_space(3))) unsigned int*)l, 16, 0, 0);
}

// ---------------- kernel 1: f32 -> bf16 conversion of Wl and x ----------------
__global__ void __launch_bounds__(256) convert_kernel(
    const float* __restrict__ Wl, const float* __restrict__ x,
    unsigned short* __restrict__ wlb, unsigned short* __restrict__ xb) {
  const long long WL4 = 16777216LL;
  const long long X4  = 524288LL;
  long long i = (long long)blockIdx.x * 256 + threadIdx.x;
  const long long stride = (long long)gridDim.x * 256;
  for (; i < WL4 + X4; i += stride) {
    float4 v;
    if (i < WL4) v = ((const float4*)Wl)[i];
    else         v = ((const float4*)x)[i - WL4];
    ushort4 o;
    o.x = f2bf(v.x); o.y = f2bf(v.y); o.z = f2bf(v.z); o.w = f2bf(v.w);
    if (i < WL4) ((ushort4*)wlb)[i] = o;
    else         ((ushort4*)xb)[i - WL4] = o;
  }
}

// ---------------- kernel 2: routing probabilities (f32 exact) ----------------
__global__ void __launch_bounds__(256) routing_kernel(
    const float* __restrict__ x, const float* __restrict__ Wd,
    const float* __restrict__ bd, float* __restrict__ rt) {
  __shared__ float xs[4][KD];
  __shared__ float sdp[4][64];
  const int tid = threadIdx.x;
  const int b0 = blockIdx.x * 4;
  const float4* xsrc = (const float4*)(x + (size_t)b0 * KD);
  float4* xdst = (float4*)&xs[0][0];
  for (int i = tid; i < KD; i += 256) xdst[i] = xsrc[i];
  __syncthreads();
  const int wv = tid >> 6, ln = tid & 63;
  const int b = b0 + wv;
  if (ln < 63) {
    const float4* wrow = (const float4*)(Wd + (size_t)ln * KD);
    const float4* xr = (const float4*)&xs[wv][0];
    float4 a = {0.f, 0.f, 0.f, 0.f};
    for (int k = 0; k < KD / 4; ++k) {
      float4 w = wrow[k], xv = xr[k];
      a.x += w.x * xv.x; a.y += w.y * xv.y; a.z += w.z * xv.z; a.w += w.w * xv.w;
    }
    float z = a.x + a.y + a.z + a.w + bd[ln];
    sdp[wv][ln] = 1.f / (1.f + __expf(-z));
  }
  __syncthreads();
  float prod = 1.f;
  int node = 0, index = ln;
  for (int d = 0; d < 6; ++d) {
    float pv = sdp[wv][node];
    prod *= (index & 1) ? (1.f - pv) : pv;
    node = node * 2 + 1 + (index & 1);
    index >>= 1;
  }
  rt[(size_t)b * NLEAF + ln] = prod;
}

// ------ kernel 3: 256x128 bf16 GEMM, wave tile 64x64, 3-slot 24KB ring, ------
// ------ ~124 VGPR -> 2 blocks/CU: cross-block LDS/MFMA overlap         ------
__global__ void __launch_bounds__(512, 4) gemm_kernel(
    const unsigned short* __restrict__ A, const unsigned short* __restrict__ B,
    const float* __restrict__ blg, _Float16* __restrict__ C, int ntile) {
  extern __shared__ char smem[];   // 3 slots x 24KB: {A 16K | B 8K}
  const int tid = threadIdx.x;
  const int w = tid >> 6, ln = tid & 63;
  const int wm = w >> 1, wn = w & 1;          // 4M x 2N wave grid
  const int g = ln >> 4, r16 = ln & 15;
  const int bid = blockIdx.x;
  const int j = bid >> 3;                     // XCD-chunked swizzle
  const int bm = (j & 7) * BM;
  const int bn = (((j >> 3) << 3) + (bid & 7)) * BN;
  const long long ldc = (long long)ntile * BN;

  // staging: A 256 rows (2 gloads), B 128 rows (1 gload); chunk-XOR on source
  const int rS = tid >> 2;                    // 0..127
  const int cS = tid & 3;
  const int csrc = cS ^ ((rS >> 1) & 3);
  const unsigned short* ga0 = A + (size_t)(bm + rS) * KD + csrc * 8;
  const unsigned short* ga1 = ga0 + (size_t)128 * KD;
  const unsigned short* gb0 = B + (size_t)(bn + rS) * KD + csrc * 8;
  const int ldsw = w * 1024;                  // wave-uniform dest

  auto STAGE = [&](int t) {                   // kk-step t -> slot t%3
    char* base = smem + (t % 3) * 24576;
    const size_t ko = (size_t)t * 32;
    gload_lds16(ga0 + ko, base + ldsw);               // A rows 0..127
    gload_lds16(ga1 + ko, base + 8192 + ldsw);        // A rows 128..255
    gload_lds16(gb0 + ko, base + 16384 + ldsw);       // B rows 0..127
  };

  // per-thread LDS read offsets (read-side swizzle), 64B rows
  int offA[4], offB[4];
#pragma unroll
  for (int mi = 0; mi < 4; ++mi) {
    const int row = wm * 64 + mi * 16 + r16;          // 0..255
    offA[mi] = row * 64 + (g ^ ((row >> 1) & 3)) * 16;
  }
#pragma unroll
  for (int ni = 0; ni < 4; ++ni) {
    const int row = wn * 64 + ni * 16 + r16;          // 0..127
    offB[ni] = 16384 + row * 64 + (g ^ ((row >> 1) & 3)) * 16;
  }

  f32x4 acc[4][4];
#pragma unroll
  for (int mi = 0; mi < 4; ++mi)
#pragma unroll
    for (int ni = 0; ni < 4; ++ni) acc[mi][ni] = (f32x4){0.f, 0.f, 0.f, 0.f};

  // prologue: stage slots 0,1; wait slot 0; publish
  STAGE(0); STAGE(1);
  asm volatile("s_waitcnt vmcnt(3)" ::: "memory");
  asm volatile("s_barrier" ::: "memory");

  for (int t = 0; t < 32; ++t) {
    const char* buf = smem + (t % 3) * 24576;
    bf16x8 af[4], bf[4];
#pragma unroll
    for (int mi = 0; mi < 4; ++mi) af[mi] = *(const bf16x8*)(buf + offA[mi]);
#pragma unroll
    for (int ni = 0; ni < 4; ++ni) bf[ni] = *(const bf16x8*)(buf + offB[ni]);
    asm volatile("s_waitcnt lgkmcnt(0)" ::: "memory");   // my reads(t) done
    __builtin_amdgcn_sched_barrier(0);
    if (t + 2 < 32) STAGE(t + 2);            // overwrites slot (t-1)%3: safe
    if (t < 30) asm volatile("s_waitcnt vmcnt(3)" ::: "memory"); // t+1 landed
    else        asm volatile("s_waitcnt vmcnt(0)" ::: "memory");
    asm volatile("s_barrier" ::: "memory");  // publish t+1; certify reads(t)
    __builtin_amdgcn_s_setprio(1);
#pragma unroll
    for (int mi = 0; mi < 4; ++mi)
#pragma unroll
      for (int ni = 0; ni < 4; ++ni)
        acc[mi][ni] = __builtin_amdgcn_mfma_f32_16x16x32_bf16(
            af[mi], bf[ni], acc[mi][ni], 0, 0, 0);
    __builtin_amdgcn_s_setprio(0);
    __builtin_amdgcn_sched_barrier(0);
  }

  // epilogue: C/D layout col=r16, row=g*4+q; fuse +bl (f32, pre-quantize)
  const int lf = bn >> 10;                   // leaf within this group
  float blv[4];
#pragma unroll
  for (int ni = 0; ni < 4; ++ni)
    blv[ni] = blg[(size_t)lf * ND + (bn & 1023) + wn * 64 + ni * 16 + r16];
#pragma unroll
  for (int mi = 0; mi < 4; ++mi)
#pragma unroll
    for (int q = 0; q < 4; ++q) {
      const long long grow = bm + wm * 64 + mi * 16 + g * 4 + q;
#pragma unroll
      for (int ni = 0; ni < 4; ++ni) {
        const int gcol = bn + wn * 64 + ni * 16 + r16;
        C[grow * ldc + gcol] = (_Float16)(acc[mi][ni][q] + blv[ni]);
      }
    }
}

// ------- kernel 4: softmax + weighted reduce, 1 wave per batch row -------
__global__ void __launch_bounds__(256) smax_kernel(
    const _Float16* __restrict__ Cg, const float* __restrict__ rt,
    float* __restrict__ out, int lpg, int l0, int first) {
  const int tid = threadIdx.x;
  const int wv = tid >> 6, ln = tid & 63;
  const int b = blockIdx.x * 4 + wv;
  const long long ldc = (long long)lpg * ND;
  const _Float16* base = Cg + (size_t)b * ldc + ln * 8;
  const float rtv = (ln < lpg) ? rt[(size_t)b * NLEAF + l0 + ln] : 0.f;

  float oacc[16];
#pragma unroll
  for (int k = 0; k < 16; ++k) oacc[k] = 0.f;

  for (int jj = 0; jj < lpg; ++jj) {
    const f16x8 h0 = *(const f16x8*)(base + jj * ND);
    const f16x8 h1 = *(const f16x8*)(base + jj * ND + 512);
    float e[16], s = 0.f;
#pragma unroll
    for (int k = 0; k < 8; ++k) { e[k] = __expf((float)h0[k]); s += e[k]; }
#pragma unroll
    for (int k = 0; k < 8; ++k) { e[8 + k] = __expf((float)h1[k]); s += e[8 + k]; }
#pragma unroll
    for (int off = 1; off < 64; off <<= 1) s += __shfl_xor(s, off);
    const float coef = __shfl(rtv, jj) / s;
#pragma unroll
    for (int k = 0; k < 16; ++k) oacc[k] += coef * e[k];
  }

  float* o0 = out + (size_t)b * ND + ln * 8;
  if (first) {
    *(float4*)o0         = (float4){oacc[0], oacc[1], oacc[2], oacc[3]};
    *(float4*)(o0 + 4)   = (float4){oacc[4], oacc[5], oacc[6], oacc[7]};
    *(float4*)(o0 + 512) = (float4){oacc[8], oacc[9], oacc[10], oacc[11]};
    *(float4*)(o0 + 516) = (float4){oacc[12], oacc[13], oacc[14], oacc[15]};
  } else {
#pragma unroll
    for (int part = 0; part < 4; ++part) {
      float* p = o0 + (part >> 1) * 512 + (part & 1) * 4;
      float4 v = *(const float4*)p;
      v.x += oacc[part * 4 + 0]; v.y += oacc[part * 4 + 1];
      v.z += oacc[part * 4 + 2]; v.w += oacc[part * 4 + 3];
      *(float4*)p = v;
    }
  }
}

extern "C" void kernel_launch(void* const* d_in, const int* in_sizes, int n_in,
                              void* d_out, int out_size, void* d_ws, size_t ws_size,
                              hipStream_t stream) {
  const float* x  = (const float*)d_in[0];
  const float* Wd = (const float*)d_in[1];
  const float* bd = (const float*)d_in[2];
  const float* Wl = (const float*)d_in[3];
  const float* bl = (const float*)d_in[4];
  float* out = (float*)d_out;
  char* ws = (char*)d_ws;
  unsigned short* wlb = (unsigned short*)(ws + WLB_OFF);
  unsigned short* xb  = (unsigned short*)(ws + XB_OFF);
  float* rt           = (float*)(ws + RT_OFF);
  _Float16* lg        = (_Float16*)(ws + LG_OFF);

  convert_kernel<<<2048, 256, 0, stream>>>(Wl, x, wlb, xb);
  routing_kernel<<<BATCH / 4, 256, 0, stream>>>(x, Wd, bd, rt);
  hipFuncSetAttribute((const void*)gemm_kernel,
                      hipFuncAttributeMaxDynamicSharedMemorySize, 73728);

  const int ngrp = (ws_size >= LG_OFF + (size_t)BATCH * NLEAF * ND * 2) ? 1 : 4;
  const int lpg = NLEAF / ngrp;
  const int ntile = lpg * (ND / BN);          // 128-col tiles
  for (int grp = 0; grp < ngrp; ++grp) {
    gemm_kernel<<<8 * ntile, 512, 73728, stream>>>(
        xb, wlb + (size_t)grp * lpg * ND * KD,
        bl + (size_t)grp * lpg * ND, lg, ntile);
    smax_kernel<<<BATCH / 4, 256, 0, stream>>>(lg, rt, out,
                                               lpg, grp * lpg, grp == 0);
  }
}